// Round 2
// baseline (328.116 us; speedup 1.0000x reference)
//
#include <hip/hip_runtime.h>
#include <hip/hip_bf16.h>

// NT-Xent loss, fused flash-style:
//   K1: normalize rows of [z1;z2] -> bf16 z_n (ws), zero reduction buffers
//   K2: fused z_n @ z_n^T via MFMA 32x32x16_bf16 + per-row sum of exp(sim/T - 10),
//       diag masked, positives sim[i,i+-N] accumulated to a scalar
//   K3: loss = (sum_i [log(rowsum_i)+10] - possum/T) / 2N
//
// Design: A-panel (64 rows x 256 K, bf16) lives in 128 VGPRs per wave; B fragments
// read directly from global (z_n is 8 MB -> L2-resident; no LDS, no bank conflicts).
// 4 waves/WG cover 256 rows and share the same B stream (L1 dedup). chunk = bid&7
// pins each 2048-col chunk to one XCD's L2.
// Clip is applied ONLY on the positive path: off-diag |sim| << 1-eps for random
// normals, diag is masked — so the hot-loop clip was pure VALU waste.

typedef __attribute__((ext_vector_type(8)))  short  short8;   // 8 x bf16 (4 VGPR)
typedef __attribute__((ext_vector_type(16))) float  f32x16;   // 32x32 MFMA acc
typedef __attribute__((ext_vector_type(4)))  unsigned short u16x4;

#define D 256           // feature dim (K), fixed by reference
#define TEMP_INV 10.0f  // 1/TEMPERATURE

__device__ __forceinline__ unsigned short f2bf(float x) {
    unsigned int u = __float_as_uint(x);
    u += 0x7FFFu + ((u >> 16) & 1u);          // round-to-nearest-even
    return (unsigned short)(u >> 16);
}

// ---------------- K1: normalize + cast to bf16, zero reduction ws ----------------
__global__ __launch_bounds__(256) void k_norm(const float* __restrict__ z1,
                                              const float* __restrict__ z2,
                                              unsigned short* __restrict__ zn,
                                              float* __restrict__ red, int N) {
    const int wv   = threadIdx.x >> 6;
    const int lane = threadIdx.x & 63;
    const int row  = blockIdx.x * 4 + wv;                 // one wave per row
    const float* src = (row < N) ? (z1 + (size_t)row * D)
                                 : (z2 + (size_t)(row - N) * D);
    float4 v = *(const float4*)(src + lane * 4);          // 64 lanes x 4 = 256
    float s = v.x * v.x + v.y * v.y + v.z * v.z + v.w * v.w;
    #pragma unroll
    for (int off = 1; off < 64; off <<= 1) s += __shfl_xor(s, off);
    float inv = 1.0f / fmaxf(sqrtf(s), 1e-6f);
    u16x4 o;
    o.x = f2bf(v.x * inv); o.y = f2bf(v.y * inv);
    o.z = f2bf(v.z * inv); o.w = f2bf(v.w * inv);
    *(u16x4*)(zn + (size_t)row * D + lane * 4) = o;

    // zero rowsum[0..2N) and possum (red[2N])
    int tid = blockIdx.x * 256 + threadIdx.x;
    int N2 = 2 * N;
    if (tid <= N2) red[tid] = 0.0f;
}

// ---------------- K2: fused sim + exp-rowsum + positives ----------------
// Grid: (N2/256 row-slices) x (8 col-chunks). Block = 256 thr = 4 waves.
// Wave w owns rows [slice*256 + w*64, +64), sweeps its chunk's 2048 cols in
// 32-col tiles. Wave tile = 64x32 = 2 MFMA frags (m=0,1) per k-step, K=256 = 16 steps.
__global__ __launch_bounds__(256, 2) void k_sim(const unsigned short* __restrict__ zn,
                                                float* __restrict__ rowsum,
                                                float* __restrict__ possum,
                                                int N2) {
    const int lane = threadIdx.x & 63;
    const int wv   = threadIdx.x >> 6;
    const int l31  = lane & 31;
    const int hi   = lane >> 5;

    const int chunk = blockIdx.x & 7;     // XCD-affine column chunk
    const int slice = blockIdx.x >> 3;
    const int ccols = N2 >> 3;            // 2048 cols per chunk
    const int r0    = slice * 256 + wv * 64;   // this wave's 64 rows
    const int c0    = chunk * ccols;

    // ---- A panel into registers: a[m][ks], rows r0 + m*32 + l31, k = ks*16 + hi*8 + j
    short8 a[2][16];
    {
        const unsigned short* p0 = zn + (size_t)(r0 + l31) * D + hi * 8;
        #pragma unroll
        for (int m = 0; m < 2; ++m) {
            const unsigned short* p = p0 + (size_t)m * 32 * D;
            #pragma unroll
            for (int ks = 0; ks < 16; ++ks)
                a[m][ks] = *(const short8*)(p + ks * 16);
        }
    }

    float ea[2][16];
    #pragma unroll
    for (int m = 0; m < 2; ++m)
        #pragma unroll
        for (int r = 0; r < 16; ++r) ea[m][r] = 0.0f;
    float posAcc = 0.0f;

    const float SC   = 14.4269504088896341f;   // 10 * log2(e)
    const float CLIP = 1.0f - 1e-6f;

    const unsigned short* bbase = zn + (size_t)(c0 + l31) * D + hi * 8;

    for (int ct = c0; ct < c0 + ccols; ct += 32, bbase += 32 * D) {
        f32x16 acc0, acc1;
        #pragma unroll
        for (int r = 0; r < 16; ++r) { acc0[r] = 0.0f; acc1[r] = 0.0f; }

        #pragma unroll
        for (int ks = 0; ks < 16; ++ks) {
            short8 b = *(const short8*)(bbase + ks * 16);
            acc0 = __builtin_amdgcn_mfma_f32_32x32x16_bf16(a[0][ks], b, acc0, 0, 0, 0);
            acc1 = __builtin_amdgcn_mfma_f32_32x32x16_bf16(a[1][ks], b, acc1, 0, 0, 0);
        }

        // epilogue: exp2(sim*SC - SC), mask diag, grab positives.
        // No clip in the hot path: off-diag |sim| << 1 for normalized random
        // vectors; diag (the only +-1 elements) is masked to 0 anyway.
        #pragma unroll
        for (int m = 0; m < 2; ++m) {
            const int rrow0 = r0 + m * 32;
            const bool isDiag = (ct == rrow0);
            const bool isPos  = (ct == rrow0 + (N2 >> 1)) || (ct == rrow0 - (N2 >> 1));
            #pragma unroll
            for (int r = 0; r < 16; ++r) {
                float s = m ? acc1[r] : acc0[r];
                float e = exp2f(fmaf(s, SC, -SC));
                if (isDiag | isPos) {           // wave-uniform branch, rare
                    int crow = (r & 3) + 8 * (r >> 2) + 4 * hi;   // C/D row in block
                    bool hit = (l31 == crow);
                    if (isDiag && hit) e = 0.0f;      // mask self-similarity
                    if (isPos  && hit)                 // clipped positive sim
                        posAcc += fminf(fmaxf(s, -CLIP), CLIP);
                }
                ea[m][r] += e;
            }
        }
    }

    // reduce exp-sums across the 32 column lanes (xor < 32 stays within half)
    #pragma unroll
    for (int m = 0; m < 2; ++m)
        #pragma unroll
        for (int r = 0; r < 16; ++r) {
            float v = ea[m][r];
            v += __shfl_xor(v, 1);  v += __shfl_xor(v, 2);  v += __shfl_xor(v, 4);
            v += __shfl_xor(v, 8);  v += __shfl_xor(v, 16);
            ea[m][r] = v;
        }
    if (l31 == 0) {                         // lanes 0 and 32 hold the 2x16 row sums
        #pragma unroll
        for (int m = 0; m < 2; ++m)
            #pragma unroll
            for (int r = 0; r < 16; ++r) {
                int row = r0 + m * 32 + (r & 3) + 8 * (r >> 2) + 4 * hi;
                atomicAdd(rowsum + row, ea[m][r]);
            }
    }

    // positives -> single scalar
    #pragma unroll
    for (int off = 1; off < 64; off <<= 1) posAcc += __shfl_xor(posAcc, off);
    if (lane == 0 && posAcc != 0.0f) atomicAdd(possum, posAcc);
}

// ---------------- K3: final scalar reduction ----------------
__global__ __launch_bounds__(1024) void k_final(const float* __restrict__ red,
                                                float* __restrict__ out, int N2) {
    __shared__ float sm[16];
    float s = 0.0f;
    for (int i = threadIdx.x; i < N2; i += 1024)
        s += __logf(red[i]);                 // lse_i = log(rowsum_i) + 10
    #pragma unroll
    for (int off = 1; off < 64; off <<= 1) s += __shfl_xor(s, off);
    const int wv = threadIdx.x >> 6, lane = threadIdx.x & 63;
    if (lane == 0) sm[wv] = s;
    __syncthreads();
    if (threadIdx.x == 0) {
        float t = 0.0f;
        #pragma unroll
        for (int w = 0; w < 16; ++w) t += sm[w];
        float possum = red[N2];
        out[0] = (t + 10.0f * (float)N2 - possum * TEMP_INV) / (float)N2;
    }
}

extern "C" void kernel_launch(void* const* d_in, const int* in_sizes, int n_in,
                              void* d_out, int out_size, void* d_ws, size_t ws_size,
                              hipStream_t stream) {
    const float* z1 = (const float*)d_in[0];
    const float* z2 = (const float*)d_in[1];
    const int N  = in_sizes[0] / D;      // 8192
    const int N2 = 2 * N;                // 16384

    unsigned short* zn = (unsigned short*)d_ws;                       // N2 x D bf16 (8 MB)
    float* red = (float*)((char*)d_ws + (size_t)N2 * D * sizeof(unsigned short));
    // red[0..N2) = rowsum, red[N2] = possum

    k_norm<<<N2 / 4, 256, 0, stream>>>(z1, z2, zn, red, N);
    k_sim<<<(N2 / 256) * 8, 256, 0, stream>>>(zn, red, red + N2, N2);
    k_final<<<1, 1024, 0, stream>>>(red, (float*)d_out, N2);
}

// Round 3
// 313.577 us; speedup vs baseline: 1.0464x; 1.0464x over previous
//
#include <hip/hip_runtime.h>
#include <hip/hip_bf16.h>

// NT-Xent loss, fused flash-style:
//   K1: normalize rows of [z1;z2] -> bf16 z_n (ws), zero reduction buffers
//   K2: fused z_n @ z_n^T via MFMA 32x32x16_bf16 + per-row sum of exp(sim/T - 10),
//       diag masked, positives sim[i,i+-N] accumulated to a scalar
//   K3: loss = (sum_i [log(rowsum_i)+10] - possum/T) / 2N
//
// R3 changes (evidence: VGPR_Count=112 < 128-reg A panel => compiler was
// rematerializing A loads every tile; MfmaUtil 21%, VALUBusy 42%, latency-bound):
//   - asm volatile("" : "+v"(a)) keep-alive pins the A panel in VGPRs
//     (opaque redefinition -> not rematerializable).
//   - __builtin_amdgcn_exp2f for the epilogue (single v_exp_f32).

typedef __attribute__((ext_vector_type(8)))  short  short8;   // 8 x bf16 (4 VGPR)
typedef __attribute__((ext_vector_type(16))) float  f32x16;   // 32x32 MFMA acc
typedef __attribute__((ext_vector_type(4)))  unsigned short u16x4;

#define D 256           // feature dim (K), fixed by reference
#define TEMP_INV 10.0f  // 1/TEMPERATURE

__device__ __forceinline__ unsigned short f2bf(float x) {
    unsigned int u = __float_as_uint(x);
    u += 0x7FFFu + ((u >> 16) & 1u);          // round-to-nearest-even
    return (unsigned short)(u >> 16);
}

// ---------------- K1: normalize + cast to bf16, zero reduction ws ----------------
__global__ __launch_bounds__(256) void k_norm(const float* __restrict__ z1,
                                              const float* __restrict__ z2,
                                              unsigned short* __restrict__ zn,
                                              float* __restrict__ red, int N) {
    const int wv   = threadIdx.x >> 6;
    const int lane = threadIdx.x & 63;
    const int row  = blockIdx.x * 4 + wv;                 // one wave per row
    const float* src = (row < N) ? (z1 + (size_t)row * D)
                                 : (z2 + (size_t)(row - N) * D);
    float4 v = *(const float4*)(src + lane * 4);          // 64 lanes x 4 = 256
    float s = v.x * v.x + v.y * v.y + v.z * v.z + v.w * v.w;
    #pragma unroll
    for (int off = 1; off < 64; off <<= 1) s += __shfl_xor(s, off);
    float inv = 1.0f / fmaxf(sqrtf(s), 1e-6f);
    u16x4 o;
    o.x = f2bf(v.x * inv); o.y = f2bf(v.y * inv);
    o.z = f2bf(v.z * inv); o.w = f2bf(v.w * inv);
    *(u16x4*)(zn + (size_t)row * D + lane * 4) = o;

    // zero rowsum[0..2N) and possum (red[2N])
    int tid = blockIdx.x * 256 + threadIdx.x;
    int N2 = 2 * N;
    if (tid <= N2) red[tid] = 0.0f;
}

// ---------------- K2: fused sim + exp-rowsum + positives ----------------
// Grid: (N2/256 row-slices) x (8 col-chunks). Block = 256 thr = 4 waves.
// Wave w owns rows [slice*256 + w*64, +64), sweeps its chunk's 2048 cols in
// 32-col tiles. Wave tile = 64x32 = 2 MFMA frags (m=0,1) per k-step, K=256 = 16 steps.
__global__ __launch_bounds__(256, 2) void k_sim(const unsigned short* __restrict__ zn,
                                                float* __restrict__ rowsum,
                                                float* __restrict__ possum,
                                                int N2) {
    const int lane = threadIdx.x & 63;
    const int wv   = threadIdx.x >> 6;
    const int l31  = lane & 31;
    const int hi   = lane >> 5;

    const int chunk = blockIdx.x & 7;     // XCD-affine column chunk
    const int slice = blockIdx.x >> 3;
    const int ccols = N2 >> 3;            // 2048 cols per chunk
    const int r0    = slice * 256 + wv * 64;   // this wave's 64 rows
    const int c0    = chunk * ccols;

    // ---- A panel into registers: a[m][ks], rows r0 + m*32 + l31, k = ks*16 + hi*8 + j
    short8 a[2][16];
    {
        const unsigned short* p0 = zn + (size_t)(r0 + l31) * D + hi * 8;
        #pragma unroll
        for (int m = 0; m < 2; ++m) {
            const unsigned short* p = p0 + (size_t)m * 32 * D;
            #pragma unroll
            for (int ks = 0; ks < 16; ++ks)
                a[m][ks] = *(const short8*)(p + ks * 16);
        }
    }
    // Pin the A panel: opaque redefinition prevents the compiler from
    // rematerializing these loads inside the tile loop (R2 evidence: VGPR=112).
    #pragma unroll
    for (int m = 0; m < 2; ++m)
        #pragma unroll
        for (int ks = 0; ks < 16; ++ks)
            asm volatile("" : "+v"(a[m][ks]));

    float ea[2][16];
    #pragma unroll
    for (int m = 0; m < 2; ++m)
        #pragma unroll
        for (int r = 0; r < 16; ++r) ea[m][r] = 0.0f;
    float posAcc = 0.0f;

    const float SC   = 14.4269504088896341f;   // 10 * log2(e)
    const float CLIP = 1.0f - 1e-6f;

    const unsigned short* bbase = zn + (size_t)(c0 + l31) * D + hi * 8;

    for (int ct = c0; ct < c0 + ccols; ct += 32, bbase += 32 * D) {
        f32x16 acc0, acc1;
        #pragma unroll
        for (int r = 0; r < 16; ++r) { acc0[r] = 0.0f; acc1[r] = 0.0f; }

        #pragma unroll
        for (int ks = 0; ks < 16; ++ks) {
            short8 b = *(const short8*)(bbase + ks * 16);
            acc0 = __builtin_amdgcn_mfma_f32_32x32x16_bf16(a[0][ks], b, acc0, 0, 0, 0);
            acc1 = __builtin_amdgcn_mfma_f32_32x32x16_bf16(a[1][ks], b, acc1, 0, 0, 0);
        }

        // epilogue: exp2(sim*SC - SC), mask diag, grab positives.
        // No clip in the hot path: off-diag |sim| << 1 for normalized random
        // vectors; diag (the only +-1 elements) is masked to 0 anyway.
        #pragma unroll
        for (int m = 0; m < 2; ++m) {
            const int rrow0 = r0 + m * 32;
            const bool isDiag = (ct == rrow0);
            const bool isPos  = (ct == rrow0 + (N2 >> 1)) || (ct == rrow0 - (N2 >> 1));
            #pragma unroll
            for (int r = 0; r < 16; ++r) {
                float s = m ? acc1[r] : acc0[r];
                float e = __builtin_amdgcn_exp2f(fmaf(s, SC, -SC));
                if (isDiag | isPos) {           // wave-uniform branch, rare
                    int crow = (r & 3) + 8 * (r >> 2) + 4 * hi;   // C/D row in block
                    bool hit = (l31 == crow);
                    if (isDiag && hit) e = 0.0f;      // mask self-similarity
                    if (isPos  && hit)                 // clipped positive sim
                        posAcc += fminf(fmaxf(s, -CLIP), CLIP);
                }
                ea[m][r] += e;
            }
        }
    }

    // reduce exp-sums across the 32 column lanes (xor < 32 stays within half)
    #pragma unroll
    for (int m = 0; m < 2; ++m)
        #pragma unroll
        for (int r = 0; r < 16; ++r) {
            float v = ea[m][r];
            v += __shfl_xor(v, 1);  v += __shfl_xor(v, 2);  v += __shfl_xor(v, 4);
            v += __shfl_xor(v, 8);  v += __shfl_xor(v, 16);
            ea[m][r] = v;
        }
    if (l31 == 0) {                         // lanes 0 and 32 hold the 2x16 row sums
        #pragma unroll
        for (int m = 0; m < 2; ++m)
            #pragma unroll
            for (int r = 0; r < 16; ++r) {
                int row = r0 + m * 32 + (r & 3) + 8 * (r >> 2) + 4 * hi;
                atomicAdd(rowsum + row, ea[m][r]);
            }
    }

    // positives -> single scalar
    #pragma unroll
    for (int off = 1; off < 64; off <<= 1) posAcc += __shfl_xor(posAcc, off);
    if (lane == 0 && posAcc != 0.0f) atomicAdd(possum, posAcc);
}

// ---------------- K3: final scalar reduction ----------------
__global__ __launch_bounds__(1024) void k_final(const float* __restrict__ red,
                                                float* __restrict__ out, int N2) {
    __shared__ float sm[16];
    float s = 0.0f;
    for (int i = threadIdx.x; i < N2; i += 1024)
        s += __logf(red[i]);                 // lse_i = log(rowsum_i) + 10
    #pragma unroll
    for (int off = 1; off < 64; off <<= 1) s += __shfl_xor(s, off);
    const int wv = threadIdx.x >> 6, lane = threadIdx.x & 63;
    if (lane == 0) sm[wv] = s;
    __syncthreads();
    if (threadIdx.x == 0) {
        float t = 0.0f;
        #pragma unroll
        for (int w = 0; w < 16; ++w) t += sm[w];
        float possum = red[N2];
        out[0] = (t + 10.0f * (float)N2 - possum * TEMP_INV) / (float)N2;
    }
}

extern "C" void kernel_launch(void* const* d_in, const int* in_sizes, int n_in,
                              void* d_out, int out_size, void* d_ws, size_t ws_size,
                              hipStream_t stream) {
    const float* z1 = (const float*)d_in[0];
    const float* z2 = (const float*)d_in[1];
    const int N  = in_sizes[0] / D;      // 8192
    const int N2 = 2 * N;                // 16384

    unsigned short* zn = (unsigned short*)d_ws;                       // N2 x D bf16 (8 MB)
    float* red = (float*)((char*)d_ws + (size_t)N2 * D * sizeof(unsigned short));
    // red[0..N2) = rowsum, red[N2] = possum

    k_norm<<<N2 / 4, 256, 0, stream>>>(z1, z2, zn, red, N);
    k_sim<<<(N2 / 256) * 8, 256, 0, stream>>>(zn, red, red + N2, N2);
    k_final<<<1, 1024, 0, stream>>>(red, (float*)d_out, N2);
}

// Round 4
// 222.794 us; speedup vs baseline: 1.4727x; 1.4075x over previous
//
#include <hip/hip_runtime.h>
#include <hip/hip_bf16.h>

// NT-Xent loss, symmetric + LDS-staged:
//   K1: normalize rows of [z1;z2] -> bf16 z_n (ws), zero reduction buffers
//   K2: one WG per block-pair (bi<=bj) of 256-row blocks. Computes the 256x256
//       sim block ONCE via MFMA; exp(sim/T-10) accumulated into rowsum[i]
//       (register ea) AND rowsum[j] (column partials, LDS colsum4) -> 2x FLOP cut.
//       B panel staged in LDS (double-buffered, global_load_lds w=16, XOR swizzle)
//       so B crosses L1 once per WG, not once per wave (R3 was L1-BW-capped).
//   K3: loss = (sum_i [log(rowsum_i)+10] - possum/T) / 2N

typedef __attribute__((ext_vector_type(8)))  short  short8;   // 8 x bf16 (4 VGPR)
typedef __attribute__((ext_vector_type(16))) float  f32x16;   // 32x32 MFMA acc
typedef __attribute__((ext_vector_type(4)))  unsigned short u16x4;

#define D 256           // feature dim (K)
#define NB 64           // 256-row blocks in 2N=16384
#define TEMP_INV 10.0f

typedef __attribute__((address_space(1))) const unsigned int as1_u32;
typedef __attribute__((address_space(3))) unsigned int       as3_u32;

__device__ __forceinline__ void gload_lds16(const void* g, void* l) {
    __builtin_amdgcn_global_load_lds((as1_u32*)g, (as3_u32*)l, 16, 0, 0);
}

__device__ __forceinline__ unsigned short f2bf(float x) {
    unsigned int u = __float_as_uint(x);
    u += 0x7FFFu + ((u >> 16) & 1u);          // round-to-nearest-even
    return (unsigned short)(u >> 16);
}

// ---------------- K1: normalize + cast to bf16, zero reduction ws ----------------
__global__ __launch_bounds__(256) void k_norm(const float* __restrict__ z1,
                                              const float* __restrict__ z2,
                                              unsigned short* __restrict__ zn,
                                              float* __restrict__ red, int N) {
    const int wv   = threadIdx.x >> 6;
    const int lane = threadIdx.x & 63;
    const int row  = blockIdx.x * 4 + wv;                 // one wave per row
    const float* src = (row < N) ? (z1 + (size_t)row * D)
                                 : (z2 + (size_t)(row - N) * D);
    float4 v = *(const float4*)(src + lane * 4);          // 64 lanes x 4 = 256
    float s = v.x * v.x + v.y * v.y + v.z * v.z + v.w * v.w;
    #pragma unroll
    for (int off = 1; off < 64; off <<= 1) s += __shfl_xor(s, off);
    float inv = 1.0f / fmaxf(sqrtf(s), 1e-6f);
    u16x4 o;
    o.x = f2bf(v.x * inv); o.y = f2bf(v.y * inv);
    o.z = f2bf(v.z * inv); o.w = f2bf(v.w * inv);
    *(u16x4*)(zn + (size_t)row * D + lane * 4) = o;

    int tid = blockIdx.x * 256 + threadIdx.x;
    int N2 = 2 * N;
    if (tid <= N2) red[tid] = 0.0f;               // rowsum[0..2N) + possum
}

// ---------------- K2: symmetric fused sim + exp-rowsum + positives ----------------
// Grid: NB*(NB+1)/2 = 2080 WGs, one per (bi<=bj) 256x256 block. 4 waves; wave w
// owns A rows [bi*256+w*64, +64) in registers; all waves share the LDS B tile
// (32 cols x 256 k, double-buffered).
__global__ __launch_bounds__(256, 2) void k_sim(const unsigned short* __restrict__ zn,
                                                float* __restrict__ rowsum,
                                                float* __restrict__ possum,
                                                int N2) {
    __shared__ __align__(16) char ldsB[2][16384];   // 32 rows x 512 B
    __shared__ float colsum4[4][256];               // per-wave column partials

    const int tid  = threadIdx.x;
    const int lane = tid & 63;
    const int wv   = tid >> 6;
    const int l31  = lane & 31;
    const int hi   = lane >> 5;

    // triangular pair decode: p -> (bi, bj), bj >= bi
    int p  = blockIdx.x;
    int bi = (int)((2.0f * NB + 1.0f - sqrtf((float)((2*NB+1)*(2*NB+1) - 8*p))) * 0.5f);
    while ((bi + 1) * NB - ((bi + 1) * bi) / 2 <= p) ++bi;
    while (bi * NB - (bi * (bi - 1)) / 2 > p) --bi;
    const int bj = bi + (p - (bi * NB - (bi * (bi - 1)) / 2));
    const bool diagWG = (bi == bj);
    const bool posWG  = (bj == bi + NB / 2);   // contains the (i, i+N) diagonal

    const int r0 = bi * 256 + wv * 64;

    // ---- A panel: a[m][ks] = zn[r0 + m*32 + l31][ks*16 + hi*8 .. +8]
    short8 a[2][16];
    {
        const unsigned short* pA = zn + (size_t)(r0 + l31) * D + hi * 8;
        #pragma unroll
        for (int m = 0; m < 2; ++m)
            #pragma unroll
            for (int ks = 0; ks < 16; ++ks)
                a[m][ks] = *(const short8*)(pA + (size_t)m * 32 * D + ks * 16);
        #pragma unroll
        for (int m = 0; m < 2; ++m)
            #pragma unroll
            for (int ks = 0; ks < 16; ++ks)
                asm volatile("" : "+v"(a[m][ks]));   // keep-alive pin
    }

    // ---- staging offsets (linear LDS dest, inverse-swizzled global source)
    // dest_local = ((q*4+wv)*64 + lane)*16 ; row = dest>>9 ; src = dest ^ ((row&31)<<4)
    int src_off[4], lds_off[4];
    #pragma unroll
    for (int q = 0; q < 4; ++q) {
        int dl = ((q * 4 + wv) * 64 + lane) * 16;
        int row = dl >> 9;
        src_off[q] = dl ^ ((row & 31) << 4);
        lds_off[q] = (q * 4 + wv) * 1024;            // wave-uniform base
    }
    const char* Bbase = (const char*)(zn + (size_t)bj * 256 * D);  // 512 B per row

#define STAGE(IT, BUF)                                                        \
    {                                                                         \
        const char* tb_ = Bbase + (IT) * 16384;                               \
        _Pragma("unroll")                                                     \
        for (int q = 0; q < 4; ++q)                                           \
            gload_lds16(tb_ + src_off[q], ldsB[BUF] + lds_off[q]);            \
    }

    float ea[2][16];
    #pragma unroll
    for (int m = 0; m < 2; ++m)
        #pragma unroll
        for (int r = 0; r < 16; ++r) ea[m][r] = 0.0f;
    float posAcc = 0.0f;

    const float SC   = 14.4269504088896341f;   // 10 * log2(e)
    const float CLIP = 1.0f - 1e-6f;
    const int   rbase = l31 * 512;              // swizzled ds_read row base

    STAGE(0, 0);
    __syncthreads();                            // drains vmcnt, tile 0 ready

    for (int it = 0; it < 8; ++it) {
        const int cur = it & 1;
        if (it < 7) STAGE(it + 1, cur ^ 1);

        f32x16 acc0, acc1;
        #pragma unroll
        for (int r = 0; r < 16; ++r) { acc0[r] = 0.0f; acc1[r] = 0.0f; }

        const char* B = ldsB[cur];
        #pragma unroll
        for (int ks = 0; ks < 16; ++ks) {
            int off = rbase + ((((ks << 1) | hi) ^ l31) << 4);   // XOR bank swizzle
            short8 b = *(const short8*)(B + off);
            acc0 = __builtin_amdgcn_mfma_f32_32x32x16_bf16(a[0][ks], b, acc0, 0, 0, 0);
            acc1 = __builtin_amdgcn_mfma_f32_32x32x16_bf16(a[1][ks], b, acc1, 0, 0, 0);
        }

        // epilogue: e = exp2(sim*SC - SC); row-acc always, col-acc if off-diag.
        float colpart = 0.0f;
        #pragma unroll
        for (int m = 0; m < 2; ++m) {
            const bool hitTile = (it == wv * 2 + m);   // local diag of the pair block
            #pragma unroll
            for (int r = 0; r < 16; ++r) {
                float s = m ? acc1[r] : acc0[r];
                float e = __builtin_amdgcn_exp2f(fmaf(s, SC, -SC));
                if ((diagWG | posWG) && hitTile) {
                    int crow = (r & 3) + 8 * (r >> 2) + 4 * hi;
                    if (l31 == crow) {
                        if (diagWG) e = 0.0f;                       // mask (i,i)
                        else posAcc += 2.0f * fminf(fmaxf(s, -CLIP), CLIP); // both pos lists
                    }
                }
                ea[m][r] += e;
                colpart  += e;
            }
        }
        if (!diagWG) {
            colpart += __shfl_xor(colpart, 32);        // fold hi half (same col)
            if (lane < 32) colsum4[wv][it * 32 + l31] = colpart;  // col owned by this tile
        }
        __syncthreads();    // staging for it+1 complete; all reads of cur done
    }

    // ---- row-side flush (rows of slice bi)
    #pragma unroll
    for (int m = 0; m < 2; ++m)
        #pragma unroll
        for (int r = 0; r < 16; ++r) {
            float v = ea[m][r];
            v += __shfl_xor(v, 1);  v += __shfl_xor(v, 2);  v += __shfl_xor(v, 4);
            v += __shfl_xor(v, 8);  v += __shfl_xor(v, 16);
            ea[m][r] = v;
        }
    if (l31 == 0) {                    // lanes 0 (hi=0) and 32 (hi=1)
        #pragma unroll
        for (int m = 0; m < 2; ++m)
            #pragma unroll
            for (int r = 0; r < 16; ++r) {
                int row = r0 + m * 32 + (r & 3) + 8 * (r >> 2) + 4 * hi;
                atomicAdd(rowsum + row, ea[m][r]);
            }
    }

    // ---- col-side flush (rows of slice bj, via symmetry)
    if (!diagWG) {
        float cv = colsum4[0][tid] + colsum4[1][tid] + colsum4[2][tid] + colsum4[3][tid];
        atomicAdd(rowsum + bj * 256 + tid, cv);
    }

    // ---- positives
    if (posWG) {
        #pragma unroll
        for (int off = 1; off < 64; off <<= 1) posAcc += __shfl_xor(posAcc, off);
        if (lane == 0) atomicAdd(possum, posAcc);
    }
#undef STAGE
}

// ---------------- K3: final scalar reduction ----------------
__global__ __launch_bounds__(1024) void k_final(const float* __restrict__ red,
                                                float* __restrict__ out, int N2) {
    __shared__ float sm[16];
    float s = 0.0f;
    for (int i = threadIdx.x; i < N2; i += 1024)
        s += __logf(red[i]);                 // lse_i = log(rowsum_i) + 10
    #pragma unroll
    for (int off = 1; off < 64; off <<= 1) s += __shfl_xor(s, off);
    const int wv = threadIdx.x >> 6, lane = threadIdx.x & 63;
    if (lane == 0) sm[wv] = s;
    __syncthreads();
    if (threadIdx.x == 0) {
        float t = 0.0f;
        #pragma unroll
        for (int w = 0; w < 16; ++w) t += sm[w];
        float possum = red[N2];
        out[0] = (t + 10.0f * (float)N2 - possum * TEMP_INV) / (float)N2;
    }
}

extern "C" void kernel_launch(void* const* d_in, const int* in_sizes, int n_in,
                              void* d_out, int out_size, void* d_ws, size_t ws_size,
                              hipStream_t stream) {
    const float* z1 = (const float*)d_in[0];
    const float* z2 = (const float*)d_in[1];
    const int N  = in_sizes[0] / D;      // 8192
    const int N2 = 2 * N;                // 16384

    unsigned short* zn = (unsigned short*)d_ws;                       // N2 x D bf16 (8 MB)
    float* red = (float*)((char*)d_ws + (size_t)N2 * D * sizeof(unsigned short));
    // red[0..N2) = rowsum, red[N2] = possum

    k_norm<<<N2 / 4, 256, 0, stream>>>(z1, z2, zn, red, N);
    k_sim<<<(NB * (NB + 1)) / 2, 256, 0, stream>>>(zn, red, red + N2, N2);
    k_final<<<1, 1024, 0, stream>>>(red, (float*)d_out, N2);
}